// Round 1
// baseline (700.804 us; speedup 1.0000x reference)
//
#include <hip/hip_runtime.h>
#include <cstdint>

#define D_MODEL 2048
#define NKV 8
#define GQ 4
#define DK 64
#define B_ 2
#define S_ 2048
#define MS (B_*S_)     // 4096
#define KVD (NKV*DK)   // 512

typedef unsigned short u16;
typedef __attribute__((ext_vector_type(8))) short bf16x8;
typedef __attribute__((ext_vector_type(4))) float f32x4;

__device__ __forceinline__ u16 f2bf(float f) {
    union { float f; uint32_t u; } x; x.f = f;
    uint32_t u = x.u;
    uint32_t r = (u + 0x7FFFu + ((u >> 16) & 1u)) >> 16;
    return (u16)r;
}
__device__ __forceinline__ float bf2f(u16 h) {
    union { uint32_t u; float f; } x; x.u = ((uint32_t)h) << 16;
    return x.f;
}

__device__ __forceinline__ void gload_lds16(const void* g, void* lds) {
    __builtin_amdgcn_global_load_lds(
        (const __attribute__((address_space(1))) void*)g,
        (__attribute__((address_space(3))) void*)lds, 16, 0, 0);
}

// ---------------- fp32 -> bf16 convert (vectorized) ----------------
__global__ void cvt_f32_bf16(const float* __restrict__ src, u16* __restrict__ dst, int n4) {
    int i = blockIdx.x * blockDim.x + threadIdx.x;
    if (i >= n4) return;
    float4 v = ((const float4*)src)[i];
    uint32_t p0 = (uint32_t)f2bf(v.x) | ((uint32_t)f2bf(v.y) << 16);
    uint32_t p1 = (uint32_t)f2bf(v.z) | ((uint32_t)f2bf(v.w) << 16);
    ((uint2*)dst)[i] = make_uint2(p0, p1);
}

// ---------------- GEMM: C[M,N] = A[M,K] @ B[N,K]^T + bias ----------------
// MODE 0: store bf16 row-major [M,N]
// MODE 1: store bf16 transposed per batch: out[(b*KVD + n)*S_ + s], m = b*S_+s
// MODE 2: store fp32 row-major [M,N]
template<int MODE>
__global__ __launch_bounds__(256)
void gemm_bt(const u16* __restrict__ A, const u16* __restrict__ Bw,
             const float* __restrict__ bias, void* __restrict__ Cout,
             int M, int N, int K) {
    __shared__ __align__(16) u16 As[128 * 32];
    __shared__ __align__(16) u16 Bs[128 * 32];
    const int tid = threadIdx.x;
    const int w = tid >> 6, l = tid & 63;
    const int m0 = blockIdx.y * 128, n0 = blockIdx.x * 128;
    const int wr = w >> 1, wc = w & 1;
    const int fr = l & 15, fq = l >> 4;

    f32x4 acc[4][4] = {};

    // staging: chunk c = w*2+j covers rows [c*16, c*16+16) x 32 k, 1KB per wave-call
    const int rowS = w * 32 + (l >> 2);     // chunk j=0 row
    const int colS = (l & 3) * 8;
    const u16* gA0 = A + (size_t)(m0 + rowS) * K + colS;
    const u16* gA1 = gA0 + (size_t)16 * K;
    const u16* gB0 = Bw + (size_t)(n0 + rowS) * K + colS;
    const u16* gB1 = gB0 + (size_t)16 * K;
    u16* lA0 = &As[(w * 2) * 512];
    u16* lA1 = &As[(w * 2 + 1) * 512];
    u16* lB0 = &Bs[(w * 2) * 512];
    u16* lB1 = &Bs[(w * 2 + 1) * 512];

    for (int k0 = 0; k0 < K; k0 += 32) {
        gload_lds16(gA0 + k0, lA0);
        gload_lds16(gA1 + k0, lA1);
        gload_lds16(gB0 + k0, lB0);
        gload_lds16(gB1 + k0, lB1);
        __syncthreads();
        bf16x8 a[4], b[4];
#pragma unroll
        for (int m = 0; m < 4; ++m)
            a[m] = *(const bf16x8*)&As[(wr * 64 + m * 16 + fr) * 32 + fq * 8];
#pragma unroll
        for (int n = 0; n < 4; ++n)
            b[n] = *(const bf16x8*)&Bs[(wc * 64 + n * 16 + fr) * 32 + fq * 8];
#pragma unroll
        for (int m = 0; m < 4; ++m)
#pragma unroll
            for (int n = 0; n < 4; ++n)
                acc[m][n] = __builtin_amdgcn_mfma_f32_16x16x32_bf16(a[m], b[n], acc[m][n], 0, 0, 0);
        __syncthreads();
    }

    // epilogue: C row = m0 + wr*64 + m*16 + fq*4 + r ; col = n0 + wc*64 + n*16 + fr
    float bv[4];
#pragma unroll
    for (int n = 0; n < 4; ++n) bv[n] = bias[n0 + wc * 64 + n * 16 + fr];
#pragma unroll
    for (int m = 0; m < 4; ++m) {
        int grow0 = m0 + wr * 64 + m * 16 + fq * 4;
#pragma unroll
        for (int n = 0; n < 4; ++n) {
            int gcol = n0 + wc * 64 + n * 16 + fr;
#pragma unroll
            for (int r = 0; r < 4; ++r) {
                float v = acc[m][n][r] + bv[n];
                int grow = grow0 + r;
                if (MODE == 0) {
                    ((u16*)Cout)[(size_t)grow * N + gcol] = f2bf(v);
                } else if (MODE == 1) {
                    int b = grow >> 11, s = grow & (S_ - 1);
                    ((u16*)Cout)[((size_t)b * KVD + gcol) * S_ + s] = f2bf(v);
                } else {
                    ((float*)Cout)[(size_t)grow * N + gcol] = v;
                }
            }
        }
    }
}

// ---------------- Flash attention (causal, GQA) ----------------
// grid: b(2) x kv(8) x g(4) x qblock(32) = 2048 blocks, 256 thr = 4 waves
// wave w handles 16 q rows: s = qb*64 + w*16 + [0,16)
__global__ __launch_bounds__(256)
void attn_fwd(const u16* __restrict__ Qp, const u16* __restrict__ Kp,
              const u16* __restrict__ Vt, u16* __restrict__ AO) {
    __shared__ __align__(16) u16 Plds[4][16 * 32];
    const int wg = blockIdx.x;
    const int qb = wg & 31;
    const int g = (wg >> 5) & 3;
    const int kv = (wg >> 7) & 7;
    const int b = wg >> 10;
    const int tid = threadIdx.x, w = tid >> 6, l = tid & 63;
    const int fr = l & 15, fq = l >> 4;
    const int h = kv * GQ + g;
    const int qrow0 = qb * 64 + w * 16;

    // Q fragments, pre-scaled by 1/sqrt(64)=0.125 (exact in bf16)
    bf16x8 aq[2];
    const u16* qptr = Qp + ((size_t)(b * S_) + qrow0 + fr) * D_MODEL + h * DK;
#pragma unroll
    for (int ks = 0; ks < 2; ++ks) {
        bf16x8 t = *(const bf16x8*)(qptr + ks * 32 + fq * 8);
#pragma unroll
        for (int j = 0; j < 8; ++j)
            t[j] = (short)f2bf(bf2f((u16)t[j]) * 0.125f);
        aq[ks] = t;
    }

    float m_run[4], l_run[4];
    f32x4 o[4] = {};
#pragma unroll
    for (int r = 0; r < 4; ++r) { m_run[r] = -1e30f; l_run[r] = 0.f; }

    const u16* kbase = Kp + (size_t)(b * S_) * KVD + kv * DK;
    const u16* vbase = Vt + ((size_t)b * KVD + kv * DK) * S_;

    const int nt = (qb + 1) * 2;  // 32-key tiles up to causal bound of the block
    for (int t = 0; t < nt; ++t) {
        const int kb0 = t * 32;
        f32x4 acc[2] = {};
#pragma unroll
        for (int nh = 0; nh < 2; ++nh)
#pragma unroll
            for (int ks = 0; ks < 2; ++ks) {
                bf16x8 bk = *(const bf16x8*)(kbase + (size_t)(kb0 + nh * 16 + fr) * KVD + ks * 32 + fq * 8);
                acc[nh] = __builtin_amdgcn_mfma_f32_16x16x32_bf16(aq[ks], bk, acc[nh], 0, 0, 0);
            }
        // causal mask + per-row max over tile
        float sc[2][4], pm[4];
#pragma unroll
        for (int r = 0; r < 4; ++r) {
            int qrow = qrow0 + fq * 4 + r;
            float s0 = (kb0 + fr) <= qrow ? acc[0][r] : -1e30f;
            float s1 = (kb0 + 16 + fr) <= qrow ? acc[1][r] : -1e30f;
            sc[0][r] = s0; sc[1][r] = s1;
            pm[r] = fmaxf(s0, s1);
        }
#pragma unroll
        for (int r = 0; r < 4; ++r) {
            pm[r] = fmaxf(pm[r], __shfl_xor(pm[r], 1));
            pm[r] = fmaxf(pm[r], __shfl_xor(pm[r], 2));
            pm[r] = fmaxf(pm[r], __shfl_xor(pm[r], 4));
            pm[r] = fmaxf(pm[r], __shfl_xor(pm[r], 8));
        }
        // online softmax update
        float p[2][4];
#pragma unroll
        for (int r = 0; r < 4; ++r) {
            float mn = fmaxf(m_run[r], pm[r]);
            float scale = __expf(m_run[r] - mn);
            m_run[r] = mn;
            float p0 = __expf(sc[0][r] - mn);
            float p1 = __expf(sc[1][r] - mn);
            p[0][r] = p0; p[1][r] = p1;
            l_run[r] = l_run[r] * scale + p0 + p1;
#pragma unroll
            for (int n = 0; n < 4; ++n) o[n][r] *= scale;
        }
        // P -> LDS (bf16), then read back as MFMA A-fragment
#pragma unroll
        for (int nh = 0; nh < 2; ++nh)
#pragma unroll
            for (int r = 0; r < 4; ++r)
                Plds[w][(fq * 4 + r) * 32 + nh * 16 + fr] = f2bf(p[nh][r]);
        bf16x8 pa = *(const bf16x8*)&Plds[w][fr * 32 + fq * 8];
        // PV: V^T gives contiguous key-axis loads
#pragma unroll
        for (int n = 0; n < 4; ++n) {
            bf16x8 bvf = *(const bf16x8*)(vbase + (size_t)(n * 16 + fr) * S_ + kb0 + fq * 8);
            o[n] = __builtin_amdgcn_mfma_f32_16x16x32_bf16(pa, bvf, o[n], 0, 0, 0);
        }
    }

    // reduce l across the 16 lanes of each row group
#pragma unroll
    for (int r = 0; r < 4; ++r) {
        float lt = l_run[r];
        lt += __shfl_xor(lt, 1);
        lt += __shfl_xor(lt, 2);
        lt += __shfl_xor(lt, 4);
        lt += __shfl_xor(lt, 8);
        l_run[r] = lt;
    }

    u16* optr = AO + ((size_t)(b * S_) + qrow0 + fq * 4) * D_MODEL + h * DK;
#pragma unroll
    for (int n = 0; n < 4; ++n)
#pragma unroll
        for (int r = 0; r < 4; ++r)
            optr[(size_t)r * D_MODEL + n * 16 + fr] = f2bf(o[n][r] / l_run[r]);
}

extern "C" void kernel_launch(void* const* d_in, const int* in_sizes, int n_in,
                              void* d_out, int out_size, void* d_ws, size_t ws_size,
                              hipStream_t stream) {
    const float* q  = (const float*)d_in[0];
    const float* k  = (const float*)d_in[1];
    const float* v  = (const float*)d_in[2];
    // d_in[3] = mask (ignored, known causal)
    const float* Wq = (const float*)d_in[4];
    const float* bq = (const float*)d_in[5];
    const float* Wk = (const float*)d_in[6];
    const float* bk = (const float*)d_in[7];
    const float* Wv = (const float*)d_in[8];
    const float* bv = (const float*)d_in[9];
    const float* Wo = (const float*)d_in[10];
    const float* bo = (const float*)d_in[11];
    float* out = (float*)d_out;

    char* ws = (char*)d_ws;
    size_t off = 0;
    auto alloc = [&](size_t bytes) -> void* {
        void* p = ws + off;
        off += (bytes + 255) & ~(size_t)255;
        return p;
    };
    u16* Xq  = (u16*)alloc((size_t)MS * D_MODEL * 2);
    u16* Xk  = (u16*)alloc((size_t)MS * D_MODEL * 2);
    u16* Xv  = (u16*)alloc((size_t)MS * D_MODEL * 2);
    u16* Wqh = (u16*)alloc((size_t)D_MODEL * D_MODEL * 2);
    u16* Wkh = (u16*)alloc((size_t)KVD * D_MODEL * 2);
    u16* Wvh = (u16*)alloc((size_t)KVD * D_MODEL * 2);
    u16* Woh = (u16*)alloc((size_t)D_MODEL * D_MODEL * 2);
    u16* Qp  = (u16*)alloc((size_t)MS * D_MODEL * 2);
    u16* Kp  = (u16*)alloc((size_t)MS * KVD * 2);
    u16* Vt  = (u16*)alloc((size_t)MS * KVD * 2);   // [b][KVD][S_]
    u16* AO  = (u16*)alloc((size_t)MS * D_MODEL * 2);

    auto cvt = [&](const float* s, u16* d, size_t n) {
        int n4 = (int)(n / 4);
        cvt_f32_bf16<<<(n4 + 255) / 256, 256, 0, stream>>>(s, d, n4);
    };
    cvt(q, Xq, (size_t)MS * D_MODEL);
    cvt(k, Xk, (size_t)MS * D_MODEL);
    cvt(v, Xv, (size_t)MS * D_MODEL);
    cvt(Wq, Wqh, (size_t)D_MODEL * D_MODEL);
    cvt(Wk, Wkh, (size_t)KVD * D_MODEL);
    cvt(Wv, Wvh, (size_t)KVD * D_MODEL);
    cvt(Wo, Woh, (size_t)D_MODEL * D_MODEL);

    // projections
    gemm_bt<0><<<dim3(D_MODEL / 128, MS / 128), 256, 0, stream>>>(Xq, Wqh, bq, Qp, MS, D_MODEL, D_MODEL);
    gemm_bt<0><<<dim3(KVD / 128, MS / 128), 256, 0, stream>>>(Xk, Wkh, bk, Kp, MS, KVD, D_MODEL);
    gemm_bt<1><<<dim3(KVD / 128, MS / 128), 256, 0, stream>>>(Xv, Wvh, bv, Vt, MS, KVD, D_MODEL);

    // attention
    attn_fwd<<<B_ * NKV * GQ * (S_ / 64), 256, 0, stream>>>(Qp, Kp, Vt, AO);

    // output projection -> fp32
    gemm_bt<2><<<dim3(D_MODEL / 128, MS / 128), 256, 0, stream>>>(AO, Woh, bo, out, MS, D_MODEL, D_MODEL);
}

// Round 2
// 442.585 us; speedup vs baseline: 1.5834x; 1.5834x over previous
//
#include <hip/hip_runtime.h>
#include <cstdint>

#define D_MODEL 2048
#define NKV 8
#define GQ 4
#define DK 64
#define B_ 2
#define S_ 2048
#define MS (B_*S_)     // 4096
#define KVD (NKV*DK)   // 512

typedef unsigned short u16;
typedef __attribute__((ext_vector_type(8))) short bf16x8;
typedef __attribute__((ext_vector_type(4))) short bf16x4;
typedef __attribute__((ext_vector_type(4))) float f32x4;
typedef __attribute__((ext_vector_type(16))) float f32x16;
typedef __attribute__((ext_vector_type(4))) unsigned short u16x4;

__device__ __forceinline__ u16 f2bf(float f) {
    union { float f; uint32_t u; } x; x.f = f;
    uint32_t u = x.u;
    uint32_t r = (u + 0x7FFFu + ((u >> 16) & 1u)) >> 16;
    return (u16)r;
}
__device__ __forceinline__ float bf2f(u16 h) {
    union { uint32_t u; float f; } x; x.u = ((uint32_t)h) << 16;
    return x.f;
}

__device__ __forceinline__ void gload_lds16(const void* g, void* lds) {
    __builtin_amdgcn_global_load_lds(
        (const __attribute__((address_space(1))) void*)g,
        (__attribute__((address_space(3))) void*)lds, 16, 0, 0);
}

// ---------------- fp32 -> bf16 convert (vectorized) ----------------
__global__ void cvt_f32_bf16(const float* __restrict__ src, u16* __restrict__ dst, int n4) {
    int i = blockIdx.x * blockDim.x + threadIdx.x;
    if (i >= n4) return;
    float4 v = ((const float4*)src)[i];
    uint32_t p0 = (uint32_t)f2bf(v.x) | ((uint32_t)f2bf(v.y) << 16);
    uint32_t p1 = (uint32_t)f2bf(v.z) | ((uint32_t)f2bf(v.w) << 16);
    ((uint2*)dst)[i] = make_uint2(p0, p1);
}

// ---------------- GEMM: C[M,N] = A[M,K] @ B[N,K]^T + bias ----------------
// MODE 0: store bf16 row-major [M,N]
// MODE 1: store bf16 transposed per batch: out[(b*KVD + n)*S_ + s], m = b*S_+s
// MODE 2: store fp32 row-major [M,N]
template<int MODE>
__global__ __launch_bounds__(256)
void gemm_bt(const u16* __restrict__ A, const u16* __restrict__ Bw,
             const float* __restrict__ bias, void* __restrict__ Cout,
             int M, int N, int K) {
    __shared__ __align__(16) u16 As[128 * 32];
    __shared__ __align__(16) u16 Bs[128 * 32];
    const int tid = threadIdx.x;
    const int w = tid >> 6, l = tid & 63;
    const int m0 = blockIdx.y * 128, n0 = blockIdx.x * 128;
    const int wr = w >> 1, wc = w & 1;
    const int fr = l & 15, fq = l >> 4;

    f32x4 acc[4][4] = {};

    const int rowS = w * 32 + (l >> 2);
    const int colS = (l & 3) * 8;
    const u16* gA0 = A + (size_t)(m0 + rowS) * K + colS;
    const u16* gA1 = gA0 + (size_t)16 * K;
    const u16* gB0 = Bw + (size_t)(n0 + rowS) * K + colS;
    const u16* gB1 = gB0 + (size_t)16 * K;
    u16* lA0 = &As[(w * 2) * 512];
    u16* lA1 = &As[(w * 2 + 1) * 512];
    u16* lB0 = &Bs[(w * 2) * 512];
    u16* lB1 = &Bs[(w * 2 + 1) * 512];

    for (int k0 = 0; k0 < K; k0 += 32) {
        gload_lds16(gA0 + k0, lA0);
        gload_lds16(gA1 + k0, lA1);
        gload_lds16(gB0 + k0, lB0);
        gload_lds16(gB1 + k0, lB1);
        __syncthreads();
        bf16x8 a[4], b[4];
#pragma unroll
        for (int m = 0; m < 4; ++m)
            a[m] = *(const bf16x8*)&As[(wr * 64 + m * 16 + fr) * 32 + fq * 8];
#pragma unroll
        for (int n = 0; n < 4; ++n)
            b[n] = *(const bf16x8*)&Bs[(wc * 64 + n * 16 + fr) * 32 + fq * 8];
#pragma unroll
        for (int m = 0; m < 4; ++m)
#pragma unroll
            for (int n = 0; n < 4; ++n)
                acc[m][n] = __builtin_amdgcn_mfma_f32_16x16x32_bf16(a[m], b[n], acc[m][n], 0, 0, 0);
        __syncthreads();
    }

    float bv[4];
#pragma unroll
    for (int n = 0; n < 4; ++n) bv[n] = bias[n0 + wc * 64 + n * 16 + fr];
#pragma unroll
    for (int m = 0; m < 4; ++m) {
        int grow0 = m0 + wr * 64 + m * 16 + fq * 4;
#pragma unroll
        for (int n = 0; n < 4; ++n) {
            int gcol = n0 + wc * 64 + n * 16 + fr;
#pragma unroll
            for (int r = 0; r < 4; ++r) {
                float v = acc[m][n][r] + bv[n];
                int grow = grow0 + r;
                if (MODE == 0) {
                    ((u16*)Cout)[(size_t)grow * N + gcol] = f2bf(v);
                } else if (MODE == 1) {
                    int b = grow >> 11, s = grow & (S_ - 1);
                    ((u16*)Cout)[((size_t)b * KVD + gcol) * S_ + s] = f2bf(v);
                } else {
                    ((float*)Cout)[(size_t)grow * N + gcol] = v;
                }
            }
        }
    }
}

// ---------------- Flash attention (causal, GQA), swapped-QK 32x32 ----------------
// Wave handles 32 q rows. Lane: q = lane&31, hi = lane>>5.
// QK^T (swapped): S^T[key][q] = mfma(K_frag, Q^T_frag); lane holds 16 scores
// (keys (r&3)+8*(r>>2)+4*hi) for its q row -> in-register softmax.
// PV: O^T[dk][q] = mfma(V^T_frag, P^T_frag); V^T loaded with permuted key axis
// so P feeds B directly after cvt_pk (no cross-lane ops).
__global__ __launch_bounds__(256)
void attn_fwd(const u16* __restrict__ Qp, const u16* __restrict__ Kp,
              const u16* __restrict__ Vt, u16* __restrict__ AO) {
    const int wg = blockIdx.x;
    const int biRev = wg >> 6;       // 0..15; 0 dispatched first
    const int rest = wg & 63;
    const int b = rest >> 5;
    const int kv = (rest >> 2) & 7;
    const int g = rest & 3;
    const int tid = threadIdx.x, w = tid >> 6, l = tid & 63;
    const int q31 = l & 31, hi = l >> 5;
    const int h = kv * GQ + g;
    const int qt = (15 - biRev) * 4 + w;   // longest q-tiles first
    const int q0 = qt * 32 + q31;          // seq row within batch

    // Q^T fragments, scaled by 1/sqrt(64) * log2(e) (exp2-domain softmax)
    const float SCALE = 0.125f * 1.44269504f;
    bf16x8 qf[4];
    const u16* qp = Qp + ((size_t)(b * S_) + q0) * D_MODEL + h * DK;
#pragma unroll
    for (int ks = 0; ks < 4; ++ks) {
        bf16x8 t = *(const bf16x8*)(qp + ks * 16 + hi * 8);
#pragma unroll
        for (int j = 0; j < 8; ++j)
            t[j] = (short)f2bf(bf2f((u16)t[j]) * SCALE);
        qf[ks] = t;
    }

    const u16* kbase = Kp + (size_t)(b * S_) * KVD + kv * DK;
    const u16* vbase = Vt + ((size_t)b * KVD + kv * DK) * S_;

    f32x16 o0 = {}, o1 = {};
    float m_run = -1e30f, l_run = 0.f;

    const int nt = qt + 1;
    for (int t = 0; t < nt; ++t) {
        const int kb0 = t * 32;
        const bool diag = (t == qt);
        // ---- QK^T (swapped) ----
        f32x16 s = {};
#pragma unroll
        for (int ks = 0; ks < 4; ++ks) {
            bf16x8 kf = *(const bf16x8*)(kbase + (size_t)(kb0 + q31) * KVD + ks * 16 + hi * 8);
            s = __builtin_amdgcn_mfma_f32_32x32x16_bf16(kf, qf[ks], s, 0, 0, 0);
        }
        // ---- causal mask (diagonal tile only) ----
        if (diag) {
#pragma unroll
            for (int r = 0; r < 16; ++r) {
                int koff = (r & 3) + 8 * (r >> 2) + 4 * hi;
                s[r] = (koff <= q31) ? s[r] : -1e30f;
            }
        }
        // ---- row max (15 in-reg + 1 cross) ----
        float pm = s[0];
#pragma unroll
        for (int r = 1; r < 16; ++r) pm = fmaxf(pm, s[r]);
        pm = fmaxf(pm, __shfl_xor(pm, 32));
        // ---- deferred rescale (THR=8 in log2 domain) ----
        if (__any(pm > m_run + 8.0f)) {
            float mn = fmaxf(m_run, pm);
            float sc = __builtin_amdgcn_exp2f(m_run - mn);
            m_run = mn;
            l_run *= sc;
#pragma unroll
            for (int r = 0; r < 16; ++r) { o0[r] *= sc; o1[r] *= sc; }
        }
        // ---- exp2 + row sum ----
        float psum = 0.f;
#pragma unroll
        for (int r = 0; r < 16; ++r) {
            float p = __builtin_amdgcn_exp2f(s[r] - m_run);
            s[r] = p;
            psum += p;
        }
        l_run += psum;
        // ---- P -> bf16 B-fragments (pure in-lane) ----
        unsigned W[8];
#pragma unroll
        for (int tt = 0; tt < 8; ++tt)
            asm("v_cvt_pk_bf16_f32 %0, %1, %2" : "=v"(W[tt]) : "v"(s[2 * tt]), "v"(s[2 * tt + 1]));
        union { unsigned u[4]; bf16x8 v; } w0, w1;
#pragma unroll
        for (int tt = 0; tt < 4; ++tt) { w0.u[tt] = W[tt]; w1.u[tt] = W[tt + 4]; }
        // ---- PV: A = V^T with permuted key axis ----
#pragma unroll
        for (int half = 0; half < 2; ++half) {
#pragma unroll
            for (int sl = 0; sl < 2; ++sl) {
                const u16* vr = vbase + (size_t)(half * 32 + q31) * S_ + kb0 + sl * 16 + 4 * hi;
                union { bf16x4 h[2]; bf16x8 v; } vf;
                vf.h[0] = *(const bf16x4*)(vr);
                vf.h[1] = *(const bf16x4*)(vr + 8);
                if (half == 0)
                    o0 = __builtin_amdgcn_mfma_f32_32x32x16_bf16(vf.v, (sl ? w1.v : w0.v), o0, 0, 0, 0);
                else
                    o1 = __builtin_amdgcn_mfma_f32_32x32x16_bf16(vf.v, (sl ? w1.v : w0.v), o1, 0, 0, 0);
            }
        }
    }

    // ---- epilogue ----
    float lt = l_run + __shfl_xor(l_run, 32);
    float rl = 1.0f / lt;
    u16* op = AO + ((size_t)(b * S_) + q0) * D_MODEL + h * DK;
#pragma unroll
    for (int half = 0; half < 2; ++half) {
#pragma unroll
        for (int rr = 0; rr < 16; rr += 4) {
            u16x4 pk;
#pragma unroll
            for (int i = 0; i < 4; ++i)
                pk[i] = f2bf((half ? o1[rr + i] : o0[rr + i]) * rl);
            *(u16x4*)(op + half * 32 + (rr >> 2) * 8 + 4 * hi) = pk;
        }
    }
}

extern "C" void kernel_launch(void* const* d_in, const int* in_sizes, int n_in,
                              void* d_out, int out_size, void* d_ws, size_t ws_size,
                              hipStream_t stream) {
    const float* q  = (const float*)d_in[0];
    const float* k  = (const float*)d_in[1];
    const float* v  = (const float*)d_in[2];
    const float* Wq = (const float*)d_in[4];
    const float* bq = (const float*)d_in[5];
    const float* Wk = (const float*)d_in[6];
    const float* bk = (const float*)d_in[7];
    const float* Wv = (const float*)d_in[8];
    const float* bv = (const float*)d_in[9];
    const float* Wo = (const float*)d_in[10];
    const float* bo = (const float*)d_in[11];
    float* out = (float*)d_out;

    char* ws = (char*)d_ws;
    size_t off = 0;
    auto alloc = [&](size_t bytes) -> void* {
        void* p = ws + off;
        off += (bytes + 255) & ~(size_t)255;
        return p;
    };
    u16* Xq  = (u16*)alloc((size_t)MS * D_MODEL * 2);
    u16* Xk  = (u16*)alloc((size_t)MS * D_MODEL * 2);
    u16* Xv  = (u16*)alloc((size_t)MS * D_MODEL * 2);
    u16* Wqh = (u16*)alloc((size_t)D_MODEL * D_MODEL * 2);
    u16* Wkh = (u16*)alloc((size_t)KVD * D_MODEL * 2);
    u16* Wvh = (u16*)alloc((size_t)KVD * D_MODEL * 2);
    u16* Woh = (u16*)alloc((size_t)D_MODEL * D_MODEL * 2);
    u16* Qp  = (u16*)alloc((size_t)MS * D_MODEL * 2);
    u16* Kp  = (u16*)alloc((size_t)MS * KVD * 2);
    u16* Vt  = (u16*)alloc((size_t)MS * KVD * 2);   // [b][KVD][S_]
    u16* AO  = (u16*)alloc((size_t)MS * D_MODEL * 2);

    auto cvt = [&](const float* s, u16* d, size_t n) {
        int n4 = (int)(n / 4);
        cvt_f32_bf16<<<(n4 + 255) / 256, 256, 0, stream>>>(s, d, n4);
    };
    cvt(q, Xq, (size_t)MS * D_MODEL);
    cvt(k, Xk, (size_t)MS * D_MODEL);
    cvt(v, Xv, (size_t)MS * D_MODEL);
    cvt(Wq, Wqh, (size_t)D_MODEL * D_MODEL);
    cvt(Wk, Wkh, (size_t)KVD * D_MODEL);
    cvt(Wv, Wvh, (size_t)KVD * D_MODEL);
    cvt(Wo, Woh, (size_t)D_MODEL * D_MODEL);

    gemm_bt<0><<<dim3(D_MODEL / 128, MS / 128), 256, 0, stream>>>(Xq, Wqh, bq, Qp, MS, D_MODEL, D_MODEL);
    gemm_bt<0><<<dim3(KVD / 128, MS / 128), 256, 0, stream>>>(Xk, Wkh, bk, Kp, MS, KVD, D_MODEL);
    gemm_bt<1><<<dim3(KVD / 128, MS / 128), 256, 0, stream>>>(Xv, Wvh, bv, Vt, MS, KVD, D_MODEL);

    attn_fwd<<<16 * 64, 256, 0, stream>>>(Qp, Kp, Vt, AO);

    gemm_bt<2><<<dim3(D_MODEL / 128, MS / 128), 256, 0, stream>>>(AO, Woh, bo, out, MS, D_MODEL, D_MODEL);
}

// Round 3
// 307.483 us; speedup vs baseline: 2.2792x; 1.4394x over previous
//
#include <hip/hip_runtime.h>
#include <cstdint>

#define D_MODEL 2048
#define NKV 8
#define GQ 4
#define DK 64
#define B_ 2
#define S_ 2048
#define MS (B_*S_)     // 4096
#define KVD (NKV*DK)   // 512

typedef unsigned short u16;
typedef __attribute__((ext_vector_type(8))) short bf16x8;
typedef __attribute__((ext_vector_type(4))) short bf16x4;
typedef __attribute__((ext_vector_type(4))) float f32x4;
typedef __attribute__((ext_vector_type(16))) float f32x16;
typedef __attribute__((ext_vector_type(4))) unsigned short u16x4;

__device__ __forceinline__ u16 f2bf(float f) {
    union { float f; uint32_t u; } x; x.f = f;
    uint32_t u = x.u;
    uint32_t r = (u + 0x7FFFu + ((u >> 16) & 1u)) >> 16;
    return (u16)r;
}
__device__ __forceinline__ float bf2f(u16 h) {
    union { uint32_t u; float f; } x; x.u = ((uint32_t)h) << 16;
    return x.f;
}

__device__ __forceinline__ void gload_lds16(const void* g, void* lds) {
    __builtin_amdgcn_global_load_lds(
        (const __attribute__((address_space(1))) void*)g,
        (__attribute__((address_space(3))) void*)lds, 16, 0, 0);
}

// ---------------- fp32 -> bf16 convert (vectorized) ----------------
__global__ void cvt_f32_bf16(const float* __restrict__ src, u16* __restrict__ dst, int n4) {
    int i = blockIdx.x * blockDim.x + threadIdx.x;
    if (i >= n4) return;
    float4 v = ((const float4*)src)[i];
    uint32_t p0 = (uint32_t)f2bf(v.x) | ((uint32_t)f2bf(v.y) << 16);
    uint32_t p1 = (uint32_t)f2bf(v.z) | ((uint32_t)f2bf(v.w) << 16);
    ((uint2*)dst)[i] = make_uint2(p0, p1);
}

// ---------------- GEMM: C[M,N] = A[M,K] @ B[N,K]^T + bias ----------------
template<int MODE>
__global__ __launch_bounds__(256)
void gemm_bt(const u16* __restrict__ A, const u16* __restrict__ Bw,
             const float* __restrict__ bias, void* __restrict__ Cout,
             int M, int N, int K) {
    __shared__ __align__(16) u16 As[128 * 32];
    __shared__ __align__(16) u16 Bs[128 * 32];
    const int tid = threadIdx.x;
    const int w = tid >> 6, l = tid & 63;
    const int m0 = blockIdx.y * 128, n0 = blockIdx.x * 128;
    const int wr = w >> 1, wc = w & 1;
    const int fr = l & 15, fq = l >> 4;

    f32x4 acc[4][4] = {};

    const int rowS = w * 32 + (l >> 2);
    const int colS = (l & 3) * 8;
    const u16* gA0 = A + (size_t)(m0 + rowS) * K + colS;
    const u16* gA1 = gA0 + (size_t)16 * K;
    const u16* gB0 = Bw + (size_t)(n0 + rowS) * K + colS;
    const u16* gB1 = gB0 + (size_t)16 * K;
    u16* lA0 = &As[(w * 2) * 512];
    u16* lA1 = &As[(w * 2 + 1) * 512];
    u16* lB0 = &Bs[(w * 2) * 512];
    u16* lB1 = &Bs[(w * 2 + 1) * 512];

    for (int k0 = 0; k0 < K; k0 += 32) {
        gload_lds16(gA0 + k0, lA0);
        gload_lds16(gA1 + k0, lA1);
        gload_lds16(gB0 + k0, lB0);
        gload_lds16(gB1 + k0, lB1);
        __syncthreads();
        bf16x8 a[4], b[4];
#pragma unroll
        for (int m = 0; m < 4; ++m)
            a[m] = *(const bf16x8*)&As[(wr * 64 + m * 16 + fr) * 32 + fq * 8];
#pragma unroll
        for (int n = 0; n < 4; ++n)
            b[n] = *(const bf16x8*)&Bs[(wc * 64 + n * 16 + fr) * 32 + fq * 8];
#pragma unroll
        for (int m = 0; m < 4; ++m)
#pragma unroll
            for (int n = 0; n < 4; ++n)
                acc[m][n] = __builtin_amdgcn_mfma_f32_16x16x32_bf16(a[m], b[n], acc[m][n], 0, 0, 0);
        __syncthreads();
    }

    float bv[4];
#pragma unroll
    for (int n = 0; n < 4; ++n) bv[n] = bias[n0 + wc * 64 + n * 16 + fr];
#pragma unroll
    for (int m = 0; m < 4; ++m) {
        int grow0 = m0 + wr * 64 + m * 16 + fq * 4;
#pragma unroll
        for (int n = 0; n < 4; ++n) {
            int gcol = n0 + wc * 64 + n * 16 + fr;
#pragma unroll
            for (int r = 0; r < 4; ++r) {
                float v = acc[m][n][r] + bv[n];
                int grow = grow0 + r;
                if (MODE == 0) {
                    ((u16*)Cout)[(size_t)grow * N + gcol] = f2bf(v);
                } else if (MODE == 1) {
                    int b = grow >> 11, s = grow & (S_ - 1);
                    ((u16*)Cout)[((size_t)b * KVD + gcol) * S_ + s] = f2bf(v);
                } else {
                    ((float*)Cout)[(size_t)grow * N + gcol] = v;
                }
            }
        }
    }
}

// ---------------- Flash attention (causal, GQA), LDS-staged K/V ----------------
// Block = 4 waves = 128 consecutive q rows (one (b,kv,g) head, qblk of 128).
// K/V tiles of 64 keys staged via global_load_lds, double-buffered, shared by
// all 4 waves. Swapped-QK 32x32 MFMA, in-register softmax, permuted-key PV.
__global__ __launch_bounds__(256, 4)
void attn_fwd(const u16* __restrict__ Qp, const u16* __restrict__ Kp,
              const u16* __restrict__ Vt, u16* __restrict__ AO) {
    __shared__ __align__(16) u16 Klds[2][4096];   // [64 keys][64 dk], slot^=(row&7)
    __shared__ __align__(16) u16 Vlds[2][4096];   // [64 dk][64 keys], slot8^=(row&14)
    const int bid = blockIdx.x;
    const int qblk = 15 - (bid >> 6);     // longest first
    const int rest = bid & 63;
    const int b = rest >> 5;
    const int kv = (rest >> 2) & 7;
    const int g = rest & 3;
    const int tid = threadIdx.x, w = tid >> 6, l = tid & 63;
    const int q31 = l & 31, hi = l >> 5;
    const int h = kv * GQ + g;
    const int qw = qblk * 128 + w * 32;
    const int q0 = qw + q31;

    const u16* kbase = Kp + (size_t)(b * S_) * KVD + kv * DK;
    const u16* vbase = Vt + ((size_t)b * KVD + kv * DK) * S_;

    // Q^T fragments, scaled by 1/sqrt(64)*log2(e)
    const float SCALE = 0.125f * 1.44269504f;
    bf16x8 qf[4];
    const u16* qp = Qp + ((size_t)(b * S_) + q0) * D_MODEL + h * DK;
#pragma unroll
    for (int ks = 0; ks < 4; ++ks) {
        bf16x8 t = *(const bf16x8*)(qp + ks * 16 + hi * 8);
#pragma unroll
        for (int j = 0; j < 8; ++j) t[j] = (short)f2bf(bf2f((u16)t[j]) * SCALE);
        qf[ks] = t;
    }

    const int nt = 2 * qblk + 2;          // 64-key tiles for this block
    const int bound = (qw + 31) >> 6;     // last active tile for this wave

    auto STAGE = [&](int t, int bufsel) {
#pragma unroll
        for (int r = 0; r < 2; ++r) {
            int idx = r * 256 + tid;
            int row = idx >> 3;
            int slotK = (idx & 7) ^ (row & 7);
            int jV = (idx & 7) ^ ((row >> 1) & 7);
            u16* kdst = &Klds[bufsel][(r * 256 + w * 64) * 8];   // wave-uniform
            u16* vdst = &Vlds[bufsel][(r * 256 + w * 64) * 8];
            gload_lds16(kbase + (size_t)(t * 64 + row) * KVD + slotK * 8, kdst);
            gload_lds16(vbase + (size_t)row * S_ + t * 64 + jV * 8, vdst);
        }
    };

    f32x16 o0 = {}, o1 = {};
    float m_run = -1e30f, l_run = 0.f;

    STAGE(0, 0);
    __syncthreads();
    int cur = 0;
    for (int t = 0; t < nt; ++t) {
        if (t + 1 < nt) STAGE(t + 1, cur ^ 1);
        if (t <= bound) {
            const u16* Kc = Klds[cur];
            const u16* Vc = Vlds[cur];
            const int base0 = t * 64, base1 = t * 64 + 32;
            const bool act1 = (base1 <= qw + 31);

            f32x16 s0 = {};
            {
                const int row = q31;
#pragma unroll
                for (int ks = 0; ks < 4; ++ks) {
                    bf16x8 kf = *(const bf16x8*)&Kc[row * 64 + ((((ks << 1) | hi)) ^ (row & 7)) * 8];
                    s0 = __builtin_amdgcn_mfma_f32_32x32x16_bf16(kf, qf[ks], s0, 0, 0, 0);
                }
            }
            f32x16 s1 = {};
            if (act1) {
                const int row = 32 + q31;
#pragma unroll
                for (int ks = 0; ks < 4; ++ks) {
                    bf16x8 kf = *(const bf16x8*)&Kc[row * 64 + ((((ks << 1) | hi)) ^ (row & 7)) * 8];
                    s1 = __builtin_amdgcn_mfma_f32_32x32x16_bf16(kf, qf[ks], s1, 0, 0, 0);
                }
            }
            if (base0 + 31 > qw) {
#pragma unroll
                for (int r = 0; r < 16; ++r) {
                    int koff = (r & 3) + 8 * (r >> 2) + 4 * hi;
                    s0[r] = (base0 + koff <= q0) ? s0[r] : -1e30f;
                }
            }
            if (act1 && (base1 + 31 > qw)) {
#pragma unroll
                for (int r = 0; r < 16; ++r) {
                    int koff = (r & 3) + 8 * (r >> 2) + 4 * hi;
                    s1[r] = (base1 + koff <= q0) ? s1[r] : -1e30f;
                }
            }
            // softmax (in-register, log2 domain)
            float pm = s0[0];
#pragma unroll
            for (int r = 1; r < 16; ++r) pm = fmaxf(pm, s0[r]);
            if (act1) {
#pragma unroll
                for (int r = 0; r < 16; ++r) pm = fmaxf(pm, s1[r]);
            }
            pm = fmaxf(pm, __shfl_xor(pm, 32));
            if (__any(pm > m_run + 8.0f)) {
                float mn = fmaxf(m_run, pm);
                float sc = __builtin_amdgcn_exp2f(m_run - mn);
                m_run = mn; l_run *= sc;
#pragma unroll
                for (int r = 0; r < 16; ++r) { o0[r] *= sc; o1[r] *= sc; }
            }
            float psum = 0.f;
#pragma unroll
            for (int r = 0; r < 16; ++r) { float p = __builtin_amdgcn_exp2f(s0[r] - m_run); s0[r] = p; psum += p; }
            if (act1) {
#pragma unroll
                for (int r = 0; r < 16; ++r) { float p = __builtin_amdgcn_exp2f(s1[r] - m_run); s1[r] = p; psum += p; }
            }
            l_run += psum;
            // P -> bf16 B-fragments (in-lane)
            unsigned W0[8], W1[8];
#pragma unroll
            for (int tt = 0; tt < 8; ++tt)
                asm("v_cvt_pk_bf16_f32 %0, %1, %2" : "=v"(W0[tt]) : "v"(s0[2 * tt]), "v"(s0[2 * tt + 1]));
            if (act1) {
#pragma unroll
                for (int tt = 0; tt < 8; ++tt)
                    asm("v_cvt_pk_bf16_f32 %0, %1, %2" : "=v"(W1[tt]) : "v"(s1[2 * tt]), "v"(s1[2 * tt + 1]));
            }
            // PV: slices 0-1 (keys 0-31)
#pragma unroll
            for (int sl = 0; sl < 2; ++sl) {
                union { unsigned u[4]; bf16x8 v; } bw;
#pragma unroll
                for (int i = 0; i < 4; ++i) bw.u[i] = W0[sl * 4 + i];
#pragma unroll
                for (int half = 0; half < 2; ++half) {
                    const int row = half * 32 + q31;
                    union { bf16x4 h4[2]; bf16x8 v; } vf;
                    int sa = (sl * 4 + hi) ^ (row & 14);
                    int sb = (sl * 4 + 2 + hi) ^ (row & 14);
                    vf.h4[0] = *(const bf16x4*)&Vc[row * 64 + sa * 4];
                    vf.h4[1] = *(const bf16x4*)&Vc[row * 64 + sb * 4];
                    if (half == 0) o0 = __builtin_amdgcn_mfma_f32_32x32x16_bf16(vf.v, bw.v, o0, 0, 0, 0);
                    else           o1 = __builtin_amdgcn_mfma_f32_32x32x16_bf16(vf.v, bw.v, o1, 0, 0, 0);
                }
            }
            // PV: slices 2-3 (keys 32-63)
            if (act1) {
#pragma unroll
                for (int sl = 2; sl < 4; ++sl) {
                    union { unsigned u[4]; bf16x8 v; } bw;
#pragma unroll
                    for (int i = 0; i < 4; ++i) bw.u[i] = W1[(sl - 2) * 4 + i];
#pragma unroll
                    for (int half = 0; half < 2; ++half) {
                        const int row = half * 32 + q31;
                        union { bf16x4 h4[2]; bf16x8 v; } vf;
                        int sa = (sl * 4 + hi) ^ (row & 14);
                        int sb = (sl * 4 + 2 + hi) ^ (row & 14);
                        vf.h4[0] = *(const bf16x4*)&Vc[row * 64 + sa * 4];
                        vf.h4[1] = *(const bf16x4*)&Vc[row * 64 + sb * 4];
                        if (half == 0) o0 = __builtin_amdgcn_mfma_f32_32x32x16_bf16(vf.v, bw.v, o0, 0, 0, 0);
                        else           o1 = __builtin_amdgcn_mfma_f32_32x32x16_bf16(vf.v, bw.v, o1, 0, 0, 0);
                    }
                }
            }
        }
        __syncthreads();   // drains vmcnt(0): next buffer ready; cur free to overwrite
        cur ^= 1;
    }

    // epilogue
    float lt = l_run + __shfl_xor(l_run, 32);
    float rl = 1.0f / lt;
    u16* op = AO + ((size_t)(b * S_) + q0) * D_MODEL + h * DK;
#pragma unroll
    for (int half = 0; half < 2; ++half) {
#pragma unroll
        for (int rr = 0; rr < 16; rr += 4) {
            u16x4 pk;
#pragma unroll
            for (int i = 0; i < 4; ++i)
                pk[i] = f2bf((half ? o1[rr + i] : o0[rr + i]) * rl);
            *(u16x4*)(op + half * 32 + (rr >> 2) * 8 + 4 * hi) = pk;
        }
    }
}

extern "C" void kernel_launch(void* const* d_in, const int* in_sizes, int n_in,
                              void* d_out, int out_size, void* d_ws, size_t ws_size,
                              hipStream_t stream) {
    const float* q  = (const float*)d_in[0];
    const float* k  = (const float*)d_in[1];
    const float* v  = (const float*)d_in[2];
    const float* Wq = (const float*)d_in[4];
    const float* bq = (const float*)d_in[5];
    const float* Wk = (const float*)d_in[6];
    const float* bk = (const float*)d_in[7];
    const float* Wv = (const float*)d_in[8];
    const float* bv = (const float*)d_in[9];
    const float* Wo = (const float*)d_in[10];
    const float* bo = (const float*)d_in[11];
    float* out = (float*)d_out;

    char* ws = (char*)d_ws;
    size_t off = 0;
    auto alloc = [&](size_t bytes) -> void* {
        void* p = ws + off;
        off += (bytes + 255) & ~(size_t)255;
        return p;
    };
    u16* Xq  = (u16*)alloc((size_t)MS * D_MODEL * 2);
    u16* Xk  = (u16*)alloc((size_t)MS * D_MODEL * 2);
    u16* Xv  = (u16*)alloc((size_t)MS * D_MODEL * 2);
    u16* Wqh = (u16*)alloc((size_t)D_MODEL * D_MODEL * 2);
    u16* Wkh = (u16*)alloc((size_t)KVD * D_MODEL * 2);
    u16* Wvh = (u16*)alloc((size_t)KVD * D_MODEL * 2);
    u16* Woh = (u16*)alloc((size_t)D_MODEL * D_MODEL * 2);
    u16* Qp  = (u16*)alloc((size_t)MS * D_MODEL * 2);
    u16* Kp  = (u16*)alloc((size_t)MS * KVD * 2);
    u16* Vt  = (u16*)alloc((size_t)MS * KVD * 2);   // [b][KVD][S_]
    u16* AO  = (u16*)alloc((size_t)MS * D_MODEL * 2);

    auto cvt = [&](const float* s, u16* d, size_t n) {
        int n4 = (int)(n / 4);
        cvt_f32_bf16<<<(n4 + 255) / 256, 256, 0, stream>>>(s, d, n4);
    };
    cvt(q, Xq, (size_t)MS * D_MODEL);
    cvt(k, Xk, (size_t)MS * D_MODEL);
    cvt(v, Xv, (size_t)MS * D_MODEL);
    cvt(Wq, Wqh, (size_t)D_MODEL * D_MODEL);
    cvt(Wk, Wkh, (size_t)KVD * D_MODEL);
    cvt(Wv, Wvh, (size_t)KVD * D_MODEL);
    cvt(Wo, Woh, (size_t)D_MODEL * D_MODEL);

    gemm_bt<0><<<dim3(D_MODEL / 128, MS / 128), 256, 0, stream>>>(Xq, Wqh, bq, Qp, MS, D_MODEL, D_MODEL);
    gemm_bt<0><<<dim3(KVD / 128, MS / 128), 256, 0, stream>>>(Xk, Wkh, bk, Kp, MS, KVD, D_MODEL);
    gemm_bt<1><<<dim3(KVD / 128, MS / 128), 256, 0, stream>>>(Xv, Wvh, bv, Vt, MS, KVD, D_MODEL);

    attn_fwd<<<16 * 64, 256, 0, stream>>>(Qp, Kp, Vt, AO);

    gemm_bt<2><<<dim3(D_MODEL / 128, MS / 128), 256, 0, stream>>>(AO, Woh, bo, out, MS, D_MODEL, D_MODEL);
}

// Round 4
// 238.595 us; speedup vs baseline: 2.9372x; 1.2887x over previous
//
#include <hip/hip_runtime.h>
#include <cstdint>

#define D_MODEL 2048
#define NKV 8
#define GQ 4
#define DK 64
#define B_ 2
#define S_ 2048
#define MS (B_*S_)     // 4096
#define KVD (NKV*DK)   // 512

typedef unsigned short u16;
typedef __attribute__((ext_vector_type(8))) short bf16x8;
typedef __attribute__((ext_vector_type(4))) short bf16x4;
typedef __attribute__((ext_vector_type(4))) float f32x4;
typedef __attribute__((ext_vector_type(16))) float f32x16;
typedef __attribute__((ext_vector_type(4))) unsigned short u16x4;

__device__ __forceinline__ u16 f2bf(float f) {
    union { float f; uint32_t u; } x; x.f = f;
    uint32_t u = x.u;
    uint32_t r = (u + 0x7FFFu + ((u >> 16) & 1u)) >> 16;
    return (u16)r;
}
__device__ __forceinline__ float bf2f(u16 h) {
    union { uint32_t u; float f; } x; x.u = ((uint32_t)h) << 16;
    return x.f;
}

__device__ __forceinline__ void gload_lds16(const void* g, void* lds) {
    __builtin_amdgcn_global_load_lds(
        (const __attribute__((address_space(1))) void*)g,
        (__attribute__((address_space(3))) void*)lds, 16, 0, 0);
}

// ---------------- fused fp32 -> bf16 convert (7 segments, one launch) ----------------
#define C1 2097152
#define C2 4194304
#define C3 6291456
#define C4 7340032
#define C5 7602176
#define C6 7864320
#define CT 8912896
__global__ void cvt_all(const float* __restrict__ q, const float* __restrict__ k,
                        const float* __restrict__ v, const float* __restrict__ wq,
                        const float* __restrict__ wk, const float* __restrict__ wv,
                        const float* __restrict__ wo,
                        u16* __restrict__ xq, u16* __restrict__ xk, u16* __restrict__ xv,
                        u16* __restrict__ wqh, u16* __restrict__ wkh, u16* __restrict__ wvh,
                        u16* __restrict__ woh) {
    for (int i = blockIdx.x * blockDim.x + threadIdx.x; i < CT; i += gridDim.x * blockDim.x) {
        const float* s; u16* d; int off;
        if (i < C1)      { s = q;  d = xq;  off = i; }
        else if (i < C2) { s = k;  d = xk;  off = i - C1; }
        else if (i < C3) { s = v;  d = xv;  off = i - C2; }
        else if (i < C4) { s = wq; d = wqh; off = i - C3; }
        else if (i < C5) { s = wk; d = wkh; off = i - C4; }
        else if (i < C6) { s = wv; d = wvh; off = i - C5; }
        else             { s = wo; d = woh; off = i - C6; }
        float4 vv = ((const float4*)s)[off];
        uint32_t p0 = (uint32_t)f2bf(vv.x) | ((uint32_t)f2bf(vv.y) << 16);
        uint32_t p1 = (uint32_t)f2bf(vv.z) | ((uint32_t)f2bf(vv.w) << 16);
        ((uint2*)d)[off] = make_uint2(p0, p1);
    }
}

// ---------------- big GEMM: 256x128 tile, BK=64, 8 waves, dbuf + counted vmcnt ----------------
// C[M,N] = A[M,K] @ Bw[N,K]^T + bias.  MODE 0: bf16 out; MODE 2: fp32 out.
// T2 swizzle: phys = la ^ (((la>>9)&1)<<5), applied on pre-swizzled global src + ds_read.
template<int MODE>
__global__ __launch_bounds__(512, 1)
void gemm256(const u16* __restrict__ A, const u16* __restrict__ Bw,
             const float* __restrict__ bias, void* __restrict__ Cout,
             int M, int N, int K) {
    __shared__ __align__(16) u16 SA[2][2][8192];  // [buf][half][128 rows x 64 k]
    __shared__ __align__(16) u16 SB[2][8192];     // [buf][128 rows x 64 k]
    const int tid = threadIdx.x;
    const int wid = tid >> 6, lane = tid & 63;
    const int fr = lane & 15, fq = lane >> 4;
    const int wr = wid >> 1, wc = wid & 1;

    // bijective XCD swizzle (nwg multiple of 8)
    const int nwg = gridDim.x;
    const int cpx = nwg >> 3;
    const int bid = blockIdx.x;
    const int sw = (bid & 7) * cpx + (bid >> 3);
    const int nbx = N >> 7;
    const int by = sw / nbx, bx = sw % nbx;
    const int m0 = by * 256, n0 = bx * 128;

    const int NTK = K >> 6;

    auto STAGE = [&](int t, int q) {
        const int k0 = t << 6;
#pragma unroll
        for (int h = 0; h < 2; ++h)
#pragma unroll
            for (int j = 0; j < 2; ++j) {
                int p = (j * 512 + wid * 64 + lane) * 16;
                int la = p ^ (((p >> 9) & 1) << 5);
                int row = la >> 7, col = (la & 127) >> 1;
                gload_lds16(A + (size_t)(m0 + h * 128 + row) * K + (k0 + col),
                            &SA[q][h][(j * 512 + wid * 64) * 8]);
            }
#pragma unroll
        for (int j = 0; j < 2; ++j) {
            int p = (j * 512 + wid * 64 + lane) * 16;
            int la = p ^ (((p >> 9) & 1) << 5);
            int row = la >> 7, col = (la & 127) >> 1;
            gload_lds16(Bw + (size_t)(n0 + row) * K + (k0 + col),
                        &SB[q][(j * 512 + wid * 64) * 8]);
        }
    };

    f32x4 acc[4][4] = {};

    STAGE(0, 0);
    STAGE(1, 1);
    asm volatile("s_waitcnt vmcnt(6)" ::: "memory");
    __builtin_amdgcn_s_barrier();
    __builtin_amdgcn_sched_barrier(0);

    const int ah = wr >> 1;
    const int arow = (wr & 1) * 64;
    const int brow = wc * 64;

    for (int t = 0; t < NTK; ++t) {
        const int q = t & 1;
        const u16* sa = &SA[q][ah][0];
        const u16* sb = &SB[q][0];
#pragma unroll
        for (int kk = 0; kk < 2; ++kk) {
            bf16x8 af[4], bfr[4];
#pragma unroll
            for (int m = 0; m < 4; ++m) {
                int la = (arow + m * 16 + fr) * 128 + kk * 64 + fq * 16;
                int ph = la ^ (((la >> 9) & 1) << 5);
                af[m] = *(const bf16x8*)((const char*)sa + ph);
            }
#pragma unroll
            for (int n = 0; n < 4; ++n) {
                int la = (brow + n * 16 + fr) * 128 + kk * 64 + fq * 16;
                int ph = la ^ (((la >> 9) & 1) << 5);
                bfr[n] = *(const bf16x8*)((const char*)sb + ph);
            }
            __builtin_amdgcn_s_setprio(1);
#pragma unroll
            for (int m = 0; m < 4; ++m)
#pragma unroll
                for (int n = 0; n < 4; ++n)
                    acc[m][n] = __builtin_amdgcn_mfma_f32_16x16x32_bf16(af[m], bfr[n], acc[m][n], 0, 0, 0);
            __builtin_amdgcn_s_setprio(0);
        }
        __builtin_amdgcn_sched_barrier(0);
        __builtin_amdgcn_s_barrier();               // all reads of buf q done
        if (t + 2 < NTK) {
            STAGE(t + 2, q);
            asm volatile("s_waitcnt vmcnt(6)" ::: "memory");   // tile t+1 landed; t+2 in flight
        } else {
            asm volatile("s_waitcnt vmcnt(0)" ::: "memory");   // tail drain
        }
        __builtin_amdgcn_sched_barrier(0);
        __builtin_amdgcn_s_barrier();               // tile t+1 visible to all waves
        __builtin_amdgcn_sched_barrier(0);
    }

    float bvv[4];
#pragma unroll
    for (int n = 0; n < 4; ++n) bvv[n] = bias[n0 + brow + n * 16 + fr];
#pragma unroll
    for (int m = 0; m < 4; ++m) {
        int grow0 = m0 + wr * 64 + m * 16 + fq * 4;
#pragma unroll
        for (int n = 0; n < 4; ++n) {
            int gcol = n0 + brow + n * 16 + fr;
#pragma unroll
            for (int r = 0; r < 4; ++r) {
                float vv = acc[m][n][r] + bvv[n];
                if (MODE == 0) ((u16*)Cout)[(size_t)(grow0 + r) * N + gcol] = f2bf(vv);
                else           ((float*)Cout)[(size_t)(grow0 + r) * N + gcol] = vv;
            }
        }
    }
}

// ---------------- fused K+V projection (z-batched 128^2 tiles) ----------------
__global__ __launch_bounds__(256)
void gemm_kv(const u16* __restrict__ Xk, const u16* __restrict__ Xv,
             const u16* __restrict__ Wk2, const u16* __restrict__ Wv2,
             const float* __restrict__ bk2, const float* __restrict__ bv2,
             u16* __restrict__ Kp, u16* __restrict__ Vt) {
    const int z = blockIdx.z;
    const u16* A  = z ? Xv : Xk;
    const u16* Bw = z ? Wv2 : Wk2;
    const float* bias = z ? bv2 : bk2;
    const int N = KVD, K = D_MODEL;

    __shared__ __align__(16) u16 As[128 * 32];
    __shared__ __align__(16) u16 Bs[128 * 32];
    const int tid = threadIdx.x;
    const int w = tid >> 6, l = tid & 63;
    const int m0 = blockIdx.y * 128, n0 = blockIdx.x * 128;
    const int wr = w >> 1, wc = w & 1;
    const int fr = l & 15, fq = l >> 4;

    f32x4 acc[4][4] = {};

    const int rowS = w * 32 + (l >> 2);
    const int colS = (l & 3) * 8;
    const u16* gA0 = A + (size_t)(m0 + rowS) * K + colS;
    const u16* gA1 = gA0 + (size_t)16 * K;
    const u16* gB0 = Bw + (size_t)(n0 + rowS) * K + colS;
    const u16* gB1 = gB0 + (size_t)16 * K;
    u16* lA0 = &As[(w * 2) * 512];
    u16* lA1 = &As[(w * 2 + 1) * 512];
    u16* lB0 = &Bs[(w * 2) * 512];
    u16* lB1 = &Bs[(w * 2 + 1) * 512];

    for (int k0 = 0; k0 < K; k0 += 32) {
        gload_lds16(gA0 + k0, lA0);
        gload_lds16(gA1 + k0, lA1);
        gload_lds16(gB0 + k0, lB0);
        gload_lds16(gB1 + k0, lB1);
        __syncthreads();
        bf16x8 a[4], b[4];
#pragma unroll
        for (int m = 0; m < 4; ++m)
            a[m] = *(const bf16x8*)&As[(wr * 64 + m * 16 + fr) * 32 + fq * 8];
#pragma unroll
        for (int n = 0; n < 4; ++n)
            b[n] = *(const bf16x8*)&Bs[(wc * 64 + n * 16 + fr) * 32 + fq * 8];
#pragma unroll
        for (int m = 0; m < 4; ++m)
#pragma unroll
            for (int n = 0; n < 4; ++n)
                acc[m][n] = __builtin_amdgcn_mfma_f32_16x16x32_bf16(a[m], b[n], acc[m][n], 0, 0, 0);
        __syncthreads();
    }

    float bv4[4];
#pragma unroll
    for (int n = 0; n < 4; ++n) bv4[n] = bias[n0 + wc * 64 + n * 16 + fr];
#pragma unroll
    for (int m = 0; m < 4; ++m) {
        int grow0 = m0 + wr * 64 + m * 16 + fq * 4;
#pragma unroll
        for (int n = 0; n < 4; ++n) {
            int gcol = n0 + wc * 64 + n * 16 + fr;
#pragma unroll
            for (int r = 0; r < 4; ++r) {
                float v = acc[m][n][r] + bv4[n];
                int grow = grow0 + r;
                if (z == 0) {
                    Kp[(size_t)grow * N + gcol] = f2bf(v);
                } else {
                    int b = grow >> 11, s = grow & (S_ - 1);
                    Vt[((size_t)b * KVD + gcol) * S_ + s] = f2bf(v);
                }
            }
        }
    }
}

// ---------------- Flash attention (causal, GQA), LDS-staged K/V ----------------
__global__ __launch_bounds__(256, 4)
void attn_fwd(const u16* __restrict__ Qp, const u16* __restrict__ Kp,
              const u16* __restrict__ Vt, u16* __restrict__ AO) {
    __shared__ __align__(16) u16 Klds[2][4096];
    __shared__ __align__(16) u16 Vlds[2][4096];
    const int bid = blockIdx.x;
    const int qblk = 15 - (bid >> 6);
    const int rest = bid & 63;
    const int b = rest >> 5;
    const int kv = (rest >> 2) & 7;
    const int g = rest & 3;
    const int tid = threadIdx.x, w = tid >> 6, l = tid & 63;
    const int q31 = l & 31, hi = l >> 5;
    const int h = kv * GQ + g;
    const int qw = qblk * 128 + w * 32;
    const int q0 = qw + q31;

    const u16* kbase = Kp + (size_t)(b * S_) * KVD + kv * DK;
    const u16* vbase = Vt + ((size_t)b * KVD + kv * DK) * S_;

    const float SCALE = 0.125f * 1.44269504f;
    bf16x8 qf[4];
    const u16* qp = Qp + ((size_t)(b * S_) + q0) * D_MODEL + h * DK;
#pragma unroll
    for (int ks = 0; ks < 4; ++ks) {
        bf16x8 t = *(const bf16x8*)(qp + ks * 16 + hi * 8);
#pragma unroll
        for (int j = 0; j < 8; ++j) t[j] = (short)f2bf(bf2f((u16)t[j]) * SCALE);
        qf[ks] = t;
    }

    const int nt = 2 * qblk + 2;
    const int bound = (qw + 31) >> 6;

    auto STAGE = [&](int t, int bufsel) {
#pragma unroll
        for (int r = 0; r < 2; ++r) {
            int idx = r * 256 + tid;
            int row = idx >> 3;
            int slotK = (idx & 7) ^ (row & 7);
            int jV = (idx & 7) ^ ((row >> 1) & 7);
            u16* kdst = &Klds[bufsel][(r * 256 + w * 64) * 8];
            u16* vdst = &Vlds[bufsel][(r * 256 + w * 64) * 8];
            gload_lds16(kbase + (size_t)(t * 64 + row) * KVD + slotK * 8, kdst);
            gload_lds16(vbase + (size_t)row * S_ + t * 64 + jV * 8, vdst);
        }
    };

    f32x16 o0 = {}, o1 = {};
    float m_run = -1e30f, l_run = 0.f;

    STAGE(0, 0);
    __syncthreads();
    int cur = 0;
    for (int t = 0; t < nt; ++t) {
        if (t + 1 < nt) STAGE(t + 1, cur ^ 1);
        if (t <= bound) {
            const u16* Kc = Klds[cur];
            const u16* Vc = Vlds[cur];
            const int base0 = t * 64, base1 = t * 64 + 32;
            const bool act1 = (base1 <= qw + 31);

            f32x16 s0 = {};
            {
                const int row = q31;
#pragma unroll
                for (int ks = 0; ks < 4; ++ks) {
                    bf16x8 kf = *(const bf16x8*)&Kc[row * 64 + ((((ks << 1) | hi)) ^ (row & 7)) * 8];
                    s0 = __builtin_amdgcn_mfma_f32_32x32x16_bf16(kf, qf[ks], s0, 0, 0, 0);
                }
            }
            f32x16 s1 = {};
            if (act1) {
                const int row = 32 + q31;
#pragma unroll
                for (int ks = 0; ks < 4; ++ks) {
                    bf16x8 kf = *(const bf16x8*)&Kc[row * 64 + ((((ks << 1) | hi)) ^ (row & 7)) * 8];
                    s1 = __builtin_amdgcn_mfma_f32_32x32x16_bf16(kf, qf[ks], s1, 0, 0, 0);
                }
            }
            if (base0 + 31 > qw) {
#pragma unroll
                for (int r = 0; r < 16; ++r) {
                    int koff = (r & 3) + 8 * (r >> 2) + 4 * hi;
                    s0[r] = (base0 + koff <= q0) ? s0[r] : -1e30f;
                }
            }
            if (act1 && (base1 + 31 > qw)) {
#pragma unroll
                for (int r = 0; r < 16; ++r) {
                    int koff = (r & 3) + 8 * (r >> 2) + 4 * hi;
                    s1[r] = (base1 + koff <= q0) ? s1[r] : -1e30f;
                }
            }
            float pm = s0[0];
#pragma unroll
            for (int r = 1; r < 16; ++r) pm = fmaxf(pm, s0[r]);
            if (act1) {
#pragma unroll
                for (int r = 0; r < 16; ++r) pm = fmaxf(pm, s1[r]);
            }
            pm = fmaxf(pm, __shfl_xor(pm, 32));
            if (__any(pm > m_run + 8.0f)) {
                float mn = fmaxf(m_run, pm);
                float sc = __builtin_amdgcn_exp2f(m_run - mn);
                m_run = mn; l_run *= sc;
#pragma unroll
                for (int r = 0; r < 16; ++r) { o0[r] *= sc; o1[r] *= sc; }
            }
            float psum = 0.f;
#pragma unroll
            for (int r = 0; r < 16; ++r) { float p = __builtin_amdgcn_exp2f(s0[r] - m_run); s0[r] = p; psum += p; }
            if (act1) {
#pragma unroll
                for (int r = 0; r < 16; ++r) { float p = __builtin_amdgcn_exp2f(s1[r] - m_run); s1[r] = p; psum += p; }
            }
            l_run += psum;
            unsigned W0[8], W1[8];
#pragma unroll
            for (int tt = 0; tt < 8; ++tt)
                asm("v_cvt_pk_bf16_f32 %0, %1, %2" : "=v"(W0[tt]) : "v"(s0[2 * tt]), "v"(s0[2 * tt + 1]));
            if (act1) {
#pragma unroll
                for (int tt = 0; tt < 8; ++tt)
                    asm("v_cvt_pk_bf16_f32 %0, %1, %2" : "=v"(W1[tt]) : "v"(s1[2 * tt]), "v"(s1[2 * tt + 1]));
            }
#pragma unroll
            for (int sl = 0; sl < 2; ++sl) {
                union { unsigned u[4]; bf16x8 v; } bw;
#pragma unroll
                for (int i = 0; i < 4; ++i) bw.u[i] = W0[sl * 4 + i];
#pragma unroll
                for (int half = 0; half < 2; ++half) {
                    const int row = half * 32 + q31;
                    union { bf16x4 h4[2]; bf16x8 v; } vf;
                    int sa = (sl * 4 + hi) ^ (row & 14);
                    int sb = (sl * 4 + 2 + hi) ^ (row & 14);
                    vf.h4[0] = *(const bf16x4*)&Vc[row * 64 + sa * 4];
                    vf.h4[1] = *(const bf16x4*)&Vc[row * 64 + sb * 4];
                    if (half == 0) o0 = __builtin_amdgcn_mfma_f32_32x32x16_bf16(vf.v, bw.v, o0, 0, 0, 0);
                    else           o1 = __builtin_amdgcn_mfma_f32_32x32x16_bf16(vf.v, bw.v, o1, 0, 0, 0);
                }
            }
            if (act1) {
#pragma unroll
                for (int sl = 2; sl < 4; ++sl) {
                    union { unsigned u[4]; bf16x8 v; } bw;
#pragma unroll
                    for (int i = 0; i < 4; ++i) bw.u[i] = W1[(sl - 2) * 4 + i];
#pragma unroll
                    for (int half = 0; half < 2; ++half) {
                        const int row = half * 32 + q31;
                        union { bf16x4 h4[2]; bf16x8 v; } vf;
                        int sa = (sl * 4 + hi) ^ (row & 14);
                        int sb = (sl * 4 + 2 + hi) ^ (row & 14);
                        vf.h4[0] = *(const bf16x4*)&Vc[row * 64 + sa * 4];
                        vf.h4[1] = *(const bf16x4*)&Vc[row * 64 + sb * 4];
                        if (half == 0) o0 = __builtin_amdgcn_mfma_f32_32x32x16_bf16(vf.v, bw.v, o0, 0, 0, 0);
                        else           o1 = __builtin_amdgcn_mfma_f32_32x32x16_bf16(vf.v, bw.v, o1, 0, 0, 0);
                    }
                }
            }
        }
        __syncthreads();
        cur ^= 1;
    }

    float lt = l_run + __shfl_xor(l_run, 32);
    float rl = 1.0f / lt;
    u16* op = AO + ((size_t)(b * S_) + q0) * D_MODEL + h * DK;
#pragma unroll
    for (int half = 0; half < 2; ++half) {
#pragma unroll
        for (int rr = 0; rr < 16; rr += 4) {
            u16x4 pk;
#pragma unroll
            for (int i = 0; i < 4; ++i)
                pk[i] = f2bf((half ? o1[rr + i] : o0[rr + i]) * rl);
            *(u16x4*)(op + half * 32 + (rr >> 2) * 8 + 4 * hi) = pk;
        }
    }
}

extern "C" void kernel_launch(void* const* d_in, const int* in_sizes, int n_in,
                              void* d_out, int out_size, void* d_ws, size_t ws_size,
                              hipStream_t stream) {
    const float* q  = (const float*)d_in[0];
    const float* k  = (const float*)d_in[1];
    const float* v  = (const float*)d_in[2];
    const float* Wq = (const float*)d_in[4];
    const float* bq = (const float*)d_in[5];
    const float* Wk = (const float*)d_in[6];
    const float* bk = (const float*)d_in[7];
    const float* Wv = (const float*)d_in[8];
    const float* bv = (const float*)d_in[9];
    const float* Wo = (const float*)d_in[10];
    const float* bo = (const float*)d_in[11];
    float* out = (float*)d_out;

    char* ws = (char*)d_ws;
    size_t off = 0;
    auto alloc = [&](size_t bytes) -> void* {
        void* p = ws + off;
        off += (bytes + 255) & ~(size_t)255;
        return p;
    };
    u16* Xq  = (u16*)alloc((size_t)MS * D_MODEL * 2);
    u16* Xk  = (u16*)alloc((size_t)MS * D_MODEL * 2);
    u16* Xv  = (u16*)alloc((size_t)MS * D_MODEL * 2);
    u16* Wqh = (u16*)alloc((size_t)D_MODEL * D_MODEL * 2);
    u16* Wkh = (u16*)alloc((size_t)KVD * D_MODEL * 2);
    u16* Wvh = (u16*)alloc((size_t)KVD * D_MODEL * 2);
    u16* Woh = (u16*)alloc((size_t)D_MODEL * D_MODEL * 2);
    u16* Qp  = (u16*)alloc((size_t)MS * D_MODEL * 2);
    u16* Kp  = (u16*)alloc((size_t)MS * KVD * 2);
    u16* Vt  = (u16*)alloc((size_t)MS * KVD * 2);
    u16* AO  = (u16*)alloc((size_t)MS * D_MODEL * 2);

    cvt_all<<<2048, 256, 0, stream>>>(q, k, v, Wq, Wk, Wv, Wo,
                                      Xq, Xk, Xv, Wqh, Wkh, Wvh, Woh);

    gemm256<0><<<dim3((D_MODEL / 128) * (MS / 256)), 512, 0, stream>>>(
        Xq, Wqh, bq, Qp, MS, D_MODEL, D_MODEL);

    gemm_kv<<<dim3(KVD / 128, MS / 128, 2), 256, 0, stream>>>(
        Xk, Xv, Wkh, Wvh, bk, bv, Kp, Vt);

    attn_fwd<<<16 * 64, 256, 0, stream>>>(Qp, Kp, Vt, AO);

    gemm256<2><<<dim3((D_MODEL / 128) * (MS / 256)), 512, 0, stream>>>(
        AO, Woh, bo, out, MS, D_MODEL, D_MODEL);
}